// Round 10
// baseline (211.999 us; speedup 1.0000x reference)
//
#include <hip/hip_runtime.h>

// YOLO loss. R1 (strided), R2 (LDS-staged), R6 (5-thr/cell) all ~70us at
// ~2.5 TB/s effective read => NOT transaction/occupancy/conflict bound.
// R7 probe: max memory-level parallelism. 2 cells/thread, 27 independent
// float4 loads (432B) per thread issued as one burst. Little's law: need
// ~9KB in flight per CU for 6.3TB/s; this gives ~100KB+.
// ws layout: double acc[64][5] (2560 B) | int flag (at byte 2560)
constexpr int NSLOTS = 64;

// --- Kernel 1: zero accumulators + detect has_object_map encoding -----------
// all dwords in {0,1} -> int32 (flag=1); {0,0x3f800000} -> f32 (flag=2);
// else packed uint8 (flag=0).
__global__ void yl_detect_zero(const unsigned int* __restrict__ hmap,
                               double* __restrict__ acc,
                               int* __restrict__ flag, int bound) {
    __shared__ int ok[2];
    const int t = threadIdx.x;
    if (t < 2) ok[t] = 1;
    __syncthreads();
    bool vi = true, vf = true;
    for (int i = t; i < bound; i += 256) {
        const unsigned int d = hmap[i];
        vi = vi && (d == 0u || d == 1u);
        vf = vf && (d == 0u || d == 0x3f800000u);
    }
    if (!vi) atomicAnd(&ok[0], 0);
    if (!vf) atomicAnd(&ok[1], 0);
    for (int i = t; i < NSLOTS * 5; i += 256) acc[i] = 0.0;
    __syncthreads();
    if (t == 0) *flag = ok[0] ? 1 : (ok[1] ? 2 : 0);
}

__device__ __forceinline__ float iou_one(float x, float y, float w, float h,
                                         float tx1, float ty1, float tx2, float ty2,
                                         float ta) {
    const float x1 = x / 14.f - 0.5f * w, y1 = y / 14.f - 0.5f * h;
    const float x2 = x / 14.f + 0.5f * w, y2 = y / 14.f + 0.5f * h;
    const float lw = fmaxf(fminf(x2, tx2) - fmaxf(x1, tx1), 0.f);
    const float lh = fmaxf(fminf(y2, ty2) - fmaxf(y1, ty1), 0.f);
    const float inter = lw * lh;
    const float a = (x2 - x1) * (y2 - y1);
    return inter / (a + ta - inter);
}

// box terms for one cell; p0..p9 are explicit scalars (no runtime arrays)
__device__ __forceinline__ void cell_box(
    float obj, float4 tbv,
    float p0, float p1, float p2, float p3, float p4,
    float p5, float p6, float p7, float p8, float p9,
    float& s_reg, float& s_conf)
{
    const float tx1 = tbv.x / 14.f - 0.5f * tbv.z, ty1 = tbv.y / 14.f - 0.5f * tbv.w;
    const float tx2 = tbv.x / 14.f + 0.5f * tbv.z, ty2 = tbv.y / 14.f + 0.5f * tbv.w;
    const float ta  = (tx2 - tx1) * (ty2 - ty1);
    const float iou1 = iou_one(p0, p1, p2, p3, tx1, ty1, tx2, ty2, ta);
    const float iou2 = iou_one(p5, p6, p7, p8, tx1, ty1, tx2, ty2, ta);
    const bool take1 = iou1 >= iou2;
    const float bx = take1 ? p0 : p5;
    const float by = take1 ? p1 : p6;
    const float bw = take1 ? p2 : p7;
    const float bh = take1 ? p3 : p8;
    const float bc = take1 ? p4 : p9;
    const float biou = take1 ? iou1 : iou2;
    const float dx = bx - tbv.x, dy = by - tbv.y;
    const float dw = sqrtf(bw) - sqrtf(tbv.z);
    const float dh = sqrtf(bh) - sqrtf(tbv.w);
    s_reg  += obj * (dx * dx + dy * dy + dw * dw + dh * dh);
    const float dc = bc - biou;
    s_conf += obj * dc * dc;
}

// --- Kernel 2: 2 cells per thread, pure-float4 burst loads ------------------
__global__ __launch_bounds__(512) void yl_main(
    const float* __restrict__ pred, const float* __restrict__ tb,
    const float* __restrict__ tc, const void* __restrict__ hmap,
    const int* __restrict__ flag_p, double* __restrict__ acc, int pairs)
{
    const int t = blockIdx.x * 512 + threadIdx.x;   // cell-pair index
    float s_obj = 0.f, s_cls = 0.f, s_no = 0.f, s_reg = 0.f, s_conf = 0.f;

    if (t < pairs) {
        const int flag = *flag_p;  // uniform scalar, issued first

        // burst: 15 + 10 + 2 = 27 independent float4 loads (432 B in flight)
        float4 P[15];
        const float4* gp = reinterpret_cast<const float4*>(pred) + (size_t)t * 15;
        #pragma unroll
        for (int i = 0; i < 15; ++i) P[i] = gp[i];
        float4 C[10];
        const float4* gc = reinterpret_cast<const float4*>(tc) + (size_t)t * 10;
        #pragma unroll
        for (int i = 0; i < 10; ++i) C[i] = gc[i];
        const float4* gb = reinterpret_cast<const float4*>(tb) + (size_t)t * 2;
        const float4 TA = gb[0], TBv = gb[1];

        float objA, objB;
        if (flag == 1)      { const int2 h = ((const int2*)hmap)[t];   objA = (float)h.x; objB = (float)h.y; }
        else if (flag == 2) { const float2 h = ((const float2*)hmap)[t]; objA = h.x; objB = h.y; }
        else                { const uchar2 h = ((const uchar2*)hmap)[t]; objA = (float)h.x; objB = (float)h.y; }

        // unpack to flat register arrays (all accesses static after unroll)
        float f[60];
        #pragma unroll
        for (int i = 0; i < 15; ++i) {
            f[4*i] = P[i].x; f[4*i+1] = P[i].y; f[4*i+2] = P[i].z; f[4*i+3] = P[i].w;
        }
        float g[40];
        #pragma unroll
        for (int i = 0; i < 10; ++i) {
            g[4*i] = C[i].x; g[4*i+1] = C[i].y; g[4*i+2] = C[i].z; g[4*i+3] = C[i].w;
        }

        // cell A: pred f[0..29], cls g[0..19]; cell B: pred f[30..59], cls g[20..39]
        float clsA = 0.f, clsB = 0.f;
        #pragma unroll
        for (int j = 0; j < 20; ++j) {
            const float da = f[10 + j] - g[j];      clsA += da * da;
            const float db = f[40 + j] - g[20 + j]; clsB += db * db;
        }
        float noA = 0.f, noB = 0.f;
        #pragma unroll
        for (int i = 0; i < 10; ++i) {
            noA += f[i] * f[i];
            noB += f[30 + i] * f[30 + i];
        }
        s_cls = objA * clsA + objB * clsB;
        s_no  = (1.f - objA) * noA + (1.f - objB) * noB;
        s_obj = objA + objB;

        cell_box(objA, TA,  f[0],  f[1],  f[2],  f[3],  f[4],
                            f[5],  f[6],  f[7],  f[8],  f[9],  s_reg, s_conf);
        cell_box(objB, TBv, f[30], f[31], f[32], f[33], f[34],
                            f[35], f[36], f[37], f[38], f[39], s_reg, s_conf);
    }

    // block reduction: wave64 shfl -> LDS across 8 waves -> spread atomics
    float vals[5] = {s_obj, s_cls, s_no, s_reg, s_conf};
    #pragma unroll
    for (int i = 0; i < 5; ++i) {
        float v = vals[i];
        #pragma unroll
        for (int off = 32; off > 0; off >>= 1) v += __shfl_down(v, off);
        vals[i] = v;
    }
    __shared__ float red[8][5];
    const int lane = threadIdx.x & 63, wid = threadIdx.x >> 6;
    if (lane == 0) {
        #pragma unroll
        for (int i = 0; i < 5; ++i) red[wid][i] = vals[i];
    }
    __syncthreads();
    if (threadIdx.x < 5) {
        float s = 0.f;
        #pragma unroll
        for (int w = 0; w < 8; ++w) s += red[w][threadIdx.x];
        atomicAdd(&acc[(blockIdx.x & (NSLOTS - 1)) * 5 + threadIdx.x], (double)s);
    }
}

// --- Kernel 3: fold 64 slots, compute the 5 outputs -------------------------
__global__ void yl_finalize(const double* __restrict__ acc, float* __restrict__ out,
                            int cells, int nbatch) {
    const int t = threadIdx.x;  // 64 threads
    double v[5];
    #pragma unroll
    for (int i = 0; i < 5; ++i) v[i] = acc[t * 5 + i];
    #pragma unroll
    for (int i = 0; i < 5; ++i) {
        #pragma unroll
        for (int off = 32; off > 0; off >>= 1) v[i] += __shfl_down(v[i], off);
    }
    if (t == 0) {
        const double n_obj = v[0], n_noobj = (double)cells - v[0];
        const float reg_loss  = (float)(v[3] * 5.0 / n_obj);
        const float conf_loss = (float)(v[4] / n_obj);
        const float no_loss   = (float)(0.5 * v[2] / n_noobj);
        const float cls_loss  = (float)(v[1] / (double)nbatch);
        out[1] = reg_loss;
        out[2] = conf_loss;
        out[3] = no_loss;
        out[4] = cls_loss;
        out[0] = reg_loss + conf_loss + no_loss + cls_loss;  // fp32 add order = reference
    }
}

extern "C" void kernel_launch(void* const* d_in, const int* in_sizes, int n_in,
                              void* d_out, int out_size, void* d_ws, size_t ws_size,
                              hipStream_t stream) {
    const float* pred = (const float*)d_in[0];
    const float* tb   = (const float*)d_in[1];
    const float* tc   = (const float*)d_in[2];
    const void*  hm   = d_in[3];
    const int cells  = in_sizes[3];          // N * S * S (even: N*196)
    const int nbatch = cells / 196;          // N (S=14)
    const int pairs  = cells / 2;
    double* acc = (double*)d_ws;
    int* flag   = (int*)((char*)d_ws + NSLOTS * 5 * sizeof(double));

    const int bound = cells / 4 < 1024 ? cells / 4 : 1024;  // safe for all encodings
    yl_detect_zero<<<1, 256, 0, stream>>>((const unsigned int*)hm, acc, flag, bound);
    const int blocks = (pairs + 511) / 512;
    yl_main<<<blocks, 512, 0, stream>>>(pred, tb, tc, hm, flag, acc, pairs);
    yl_finalize<<<1, 64, 0, stream>>>(acc, (float*)d_out, cells, nbatch);
}